// Round 7
// baseline (1099.516 us; speedup 1.0000x reference)
//
#include <hip/hip_runtime.h>

// HyperNetSIR: x(N,3) f32, H(E,N) f32 0/1 mask (density 0.002), beta(N), gamma(N), steps(int)
// out: (steps, N, 3) f32 trajectory.
//
// v6 strategy:
//  * build_adjacency v6: two-pass. Pass A = pure streaming scan (plain loads,
//    L2-cached) emitting per-wave 64-bit nonzero ballot masks into LDS --
//    branch-free, issue-lean, BW-bound. Pass B = revisit only nonzero quads
//    (~0.8%, L2-hit) for the divergent LDS-atomic compaction. v5b interleaved
//    the atomics into the stream loop and ran at 1.6 TB/s (4x under ceiling).
//  * sir_steps: 128 blocks x 1024 threads, persistent, flag barrier.
//    Rounds 2-6 showed step time (9.9us) is insensitive to block count and
//    barrier topology -> the cost is the RMW-arrive + poll-read storm on the
//    L3 atomic unit. v6 barrier: arrive = plain sc STORE of a monotonic phase
//    number to the block's own flag word (no RMW anywhere); wait = wave 0
//    polls all 128 flags with two coalesced 64-lane sc loads + __ballot
//    (detection = one pipelined L3 read, no atomic unit).
//    Phases unchanged: register-preloaded dummy-padded adjacency, coherent
//    I/y exchange, tx-contiguous ownership, traj store overlapping the poll.

#define EDGE_CAP 96   // max nodes per edge (mean 40, sigma 6.3)
#define NODE_CAP 32   // max edges per node (mean 10, sigma 3.2)
#define NIDX_REG 16   // node-adjacency indices held in registers (P(cnt>16) ~ 3%)
#define COOP_BLOCKS 128
#define COOP_THREADS 1024
#define NFLAGS 128    // == COOP_BLOCKS; one u32 flag per block

typedef unsigned int uint4_ev __attribute__((ext_vector_type(4)));

__global__ void zero_counts_kernel(int* edge_cnt, int* node_cnt, unsigned* flags,
                                   int n_edges, int n_nodes) {
    int i = blockIdx.x * blockDim.x + threadIdx.x;
    if (i < NFLAGS) flags[i] = 0u;
    if (i < n_edges) edge_cnt[i] = 0;
    if (i < n_nodes) node_cnt[i] = 0;
}

// One block (256 threads) per edge row.
// Pass A: stream the row with plain 16B loads (lands in L2), per wave-iter
//         write one 64-bit "quad has nonzero" ballot mask to LDS.
// Pass B: walk set bits only (~40 of 5000 quads), reload those quads from L2,
//         LDS-atomic compact the nonzero column indices.
// Writeout: coalesced edge list + batched global atomics for node lists.
__global__ void build_adjacency_kernel(const float* __restrict__ H,
                                       int* __restrict__ edge_cnt,
                                       int* __restrict__ edge_nodes,
                                       int* __restrict__ node_cnt,
                                       int* __restrict__ node_edges,
                                       int n_nodes) {
    __shared__ int cnt;
    __shared__ int cols[EDGE_CAP];
    __shared__ unsigned long long qmask[128];   // supports n_nodes <= 32768
    const int e  = blockIdx.x;
    const int tx = threadIdx.x;
    if (tx == 0) cnt = 0;
    const float* row = H + (size_t)e * n_nodes;
    const uint4_ev* row4 = (const uint4_ev*)row;
    const int n4 = n_nodes >> 2;
    const int niter = (n4 + 255) >> 8;          // 256 threads -> 256 quads/iter

    // ---- pass A: branch-free streaming scan ----
    for (int i = 0; i < niter; ++i) {
        int q = (i << 8) + tx;
        uint4_ev v = {0u, 0u, 0u, 0u};
        if (q < n4) v = row4[q];
        unsigned long long m = __ballot((v.x | v.y | v.z | v.w) != 0u);
        if ((tx & 63) == 0) qmask[(i << 2) + (tx >> 6)] = m;
    }
    __syncthreads();

    // ---- pass B: sparse revisit of nonzero quads (L2-hot) ----
    const int nslots = niter << 2;
    for (int sIdx = tx; sIdx < nslots; sIdx += blockDim.x) {
        unsigned long long m = qmask[sIdx];
        int qbase = ((sIdx >> 2) << 8) + ((sIdx & 3) << 6);
        while (m) {
            int lane = __builtin_ctzll(m); m &= m - 1;
            int q = qbase + lane;
            uint4_ev v = row4[q];               // L2 hit
            int cbase = q << 2;
            if (v.x) { int p = atomicAdd(&cnt, 1); if (p < EDGE_CAP) cols[p] = cbase; }
            if (v.y) { int p = atomicAdd(&cnt, 1); if (p < EDGE_CAP) cols[p] = cbase + 1; }
            if (v.z) { int p = atomicAdd(&cnt, 1); if (p < EDGE_CAP) cols[p] = cbase + 2; }
            if (v.w) { int p = atomicAdd(&cnt, 1); if (p < EDGE_CAP) cols[p] = cbase + 3; }
        }
    }
    if (tx == 0) {   // tail (n_nodes not multiple of 4)
        for (int c = n4 << 2; c < n_nodes; ++c)
            if (row[c] != 0.0f) { int p = atomicAdd(&cnt, 1); if (p < EDGE_CAP) cols[p] = c; }
    }
    __syncthreads();

    // ---- writeout ----
    int cn = min(cnt, EDGE_CAP);
    if (tx == 0) edge_cnt[e] = cn;
    for (int i = tx; i < cn; i += blockDim.x) {
        int c = cols[i];
        edge_nodes[e * EDGE_CAP + i] = c;
        int q = atomicAdd(&node_cnt[c], 1);     // device-scope, batched
        if (q < NODE_CAP) node_edges[c * NODE_CAP + q] = e;
    }
}

// Coherent (cross-XCD) access helpers: sc-flagged, bypass non-coherent L1/L2.
__device__ __forceinline__ float coh_load(const float* p) {
    return __hip_atomic_load(p, __ATOMIC_RELAXED, __HIP_MEMORY_SCOPE_AGENT);
}
__device__ __forceinline__ void coh_storef(float* p, float v) {
    __hip_atomic_store(p, v, __ATOMIC_RELAXED, __HIP_MEMORY_SCOPE_AGENT);
}
__device__ __forceinline__ unsigned coh_loadu(const unsigned* p) {
    return __hip_atomic_load(p, __ATOMIC_RELAXED, __HIP_MEMORY_SCOPE_AGENT);
}
__device__ __forceinline__ void coh_storeu(unsigned* p, unsigned v) {
    __hip_atomic_store(p, v, __ATOMIC_RELAXED, __HIP_MEMORY_SCOPE_AGENT);
}

// Flag barrier, no RMWs. flags[b] = monotonic phase number published by block
// b. bar_pub: drain my coherent data stores (per-wave vmcnt0), block-sync
// (whole block arrived, all waves' stores drained), thread0 sc-stores the
// phase. bar_poll: wave 0 reads all 128 flags with two coalesced 64-lane sc
// loads; __ballot detects "all >= ph". Monotonic flags + relaxed loads: stale
// reads only delay, never false-positive.
__device__ __forceinline__ void bar_pub(unsigned* flags, unsigned ph) {
    asm volatile("s_waitcnt vmcnt(0)" ::: "memory");
    __syncthreads();
    if (threadIdx.x == 0) coh_storeu(&flags[blockIdx.x], ph);
}
__device__ __forceinline__ void bar_poll(unsigned* flags, unsigned ph) {
    if (threadIdx.x < 64) {          // wave 0 polls; other waves park at barrier
        for (;;) {
            unsigned a = coh_loadu(&flags[threadIdx.x]);
            unsigned b = coh_loadu(&flags[64 + threadIdx.x]);
            if (__ballot((a < ph) || (b < ph)) == 0ull) break;
            __builtin_amdgcn_s_sleep(1);
        }
    }
    __syncthreads();
    asm volatile("" ::: "memory");
}

// All SIR steps in one persistent kernel.
// Requires: gridDim == NFLAGS == 128; n_nodes <= node_chunk*gridDim with
// node_chunk <= blockDim; n_edges <= (blockDim/16)*gridDim.
__global__ __launch_bounds__(COOP_THREADS) void sir_steps_kernel(
        const float* __restrict__ x,
        const int* __restrict__ edge_cnt, const int* __restrict__ edge_nodes,
        const int* __restrict__ node_cnt, const int* __restrict__ node_edges,
        const float* __restrict__ beta, const float* __restrict__ gamma,
        float* __restrict__ y, float* __restrict__ I,
        float* __restrict__ out,
        int n_nodes, int n_edges, int steps, unsigned* flags) {
    const int b  = blockIdx.x;
    const int tx = threadIdx.x;

    // ---- tx-contiguous chunked ownership ----
    const int node_chunk = (n_nodes + gridDim.x - 1) / gridDim.x;   // 157
    const int edge_chunk = (n_edges + gridDim.x - 1) / gridDim.x;   // 40
    const int n = b * node_chunk + tx;
    const bool own = (tx < node_chunk) && (n < n_nodes);

    const int k = tx >> 4, gl = tx & 15;       // 16 lanes per edge, 64 groups/block
    const int e = b * edge_chunk + k;
    const bool has_edge = (k < edge_chunk) && (e < n_edges);

    // ---- preload adjacency into registers (dummy-padded: I[n_nodes]=y[n_edges]=0) ----
    int ecnt = 0;
    const int* en = edge_nodes;
    if (has_edge) { ecnt = min(edge_cnt[e], EDGE_CAP); en = edge_nodes + e * EDGE_CAP; }
    int eidx[6];
    #pragma unroll
    for (int i = 0; i < 6; ++i) {
        int j = i * 16 + gl;
        eidx[i] = (has_edge && j < ecnt) ? en[j] : n_nodes;
    }

    int ncnt = 0;
    const int* ne = node_edges;
    float bet = 0.0f, gam = 0.0f;
    if (own) { ncnt = min(node_cnt[n], NODE_CAP); ne = node_edges + n * NODE_CAP;
               bet = beta[n]; gam = gamma[n]; }
    int nidx[NIDX_REG];
    #pragma unroll
    for (int i = 0; i < NIDX_REG; ++i)
        nidx[i] = (own && i < ncnt) ? ne[i] : n_edges;

    // ---- init: state to regs, publish I, dummies, traj[0] ----
    float s = 0.0f, iv = 0.0f, r = 0.0f;
    if (own) {
        s = x[n * 3 + 0]; iv = x[n * 3 + 1]; r = x[n * 3 + 2];
        coh_storef(&I[n], iv);
        out[n * 3 + 0] = s; out[n * 3 + 1] = iv; out[n * 3 + 2] = r;
    }
    if (b == 0 && tx == 0) { coh_storef(&I[n_nodes], 0.0f); coh_storef(&y[n_edges], 0.0f); }
    unsigned ph = 1;
    bar_pub(flags, ph); bar_poll(flags, ph);

    for (int t = 1; t < steps; ++t) {
        // ---- edge phase: y[e] = sum I over edge members (16 lanes/edge) ----
        if (has_edge) {
            float a0 = coh_load(&I[eidx[0]]);
            float a1 = coh_load(&I[eidx[1]]);
            float a2 = coh_load(&I[eidx[2]]);
            float a3 = coh_load(&I[eidx[3]]);
            float a4 = coh_load(&I[eidx[4]]);
            float a5 = coh_load(&I[eidx[5]]);
            float acc = a0 + a1 + a2 + a3 + a4 + a5;   // trailing dummies add exact 0
            acc += __shfl_down(acc, 8, 16);
            acc += __shfl_down(acc, 4, 16);
            acc += __shfl_down(acc, 2, 16);
            acc += __shfl_down(acc, 1, 16);
            if (gl == 0) coh_storef(&y[e], acc);
        }
        ++ph; bar_pub(flags, ph); bar_poll(flags, ph);

        // ---- node phase: z = sum y over incident edges; SIR update in regs ----
        if (own) {
            float tv[NIDX_REG];
            #pragma unroll
            for (int i = 0; i < NIDX_REG; ++i) tv[i] = coh_load(&y[nidx[i]]);
            float z = 0.0f;
            #pragma unroll
            for (int i = 0; i < NIDX_REG; ++i) z += tv[i];   // in-order, dummies exact 0
            for (int i = NIDX_REG; i < ncnt; ++i) z += coh_load(&y[ne[i]]);  // rare tail
            float nc = bet * s * z;
            float nr = gam * iv;
            float s2 = fmaxf(s - nc, 0.0f);
            float i2 = fmaxf(iv + nc - nr, 0.0f);
            float r2 = fmaxf(r + nr, 0.0f);
            float inv = 1.0f / (s2 + i2 + r2);
            s = s2 * inv; iv = i2 * inv; r = r2 * inv;
            coh_storef(&I[n], iv);
        }
        ++ph; bar_pub(flags, ph);
        if (own) {   // traj store (host-consumed only) overlaps the poll
            float* ot = out + (size_t)t * n_nodes * 3 + (size_t)n * 3;
            ot[0] = s; ot[1] = iv; ot[2] = r;
        }
        if (t + 1 < steps) bar_poll(flags, ph);
    }
}

extern "C" void kernel_launch(void* const* d_in, const int* in_sizes, int n_in,
                              void* d_out, int out_size, void* d_ws, size_t ws_size,
                              hipStream_t stream) {
    const float* x     = (const float*)d_in[0];
    const float* H     = (const float*)d_in[1];
    const float* beta  = (const float*)d_in[2];
    const float* gamma = (const float*)d_in[3];
    float* out = (float*)d_out;

    const int n_nodes = in_sizes[0] / 3;                 // 20000
    const int n_edges = in_sizes[1] / n_nodes;           // 5000
    const int steps   = out_size / in_sizes[0];          // 50

    // workspace carve-up (ints/floats are both 4B)
    char* ws = (char*)d_ws;
    unsigned* flags   = (unsigned*)ws;                    ws += (size_t)NFLAGS * 4;
    int*   edge_cnt   = (int*)ws;                         ws += (size_t)n_edges * 4;
    int*   node_cnt   = (int*)ws;                         ws += (size_t)n_nodes * 4;
    int*   edge_nodes = (int*)ws;                         ws += (size_t)n_edges * EDGE_CAP * 4;
    int*   node_edges = (int*)ws;                         ws += (size_t)n_nodes * NODE_CAP * 4;
    float* y          = (float*)ws;                       ws += ((size_t)n_edges + 1) * 4;
    float* I          = (float*)ws;                       ws += ((size_t)n_nodes + 1) * 4;

    // 1. zero counters + flags (ws is poisoned 0xAA each call)
    {
        int mx = max(n_edges, max(n_nodes, (int)NFLAGS));
        zero_counts_kernel<<<(mx + 255) / 256, 256, 0, stream>>>(edge_cnt, node_cnt, flags,
                                                                 n_edges, n_nodes);
    }
    // 2. extract sparsity of H (the one unavoidable 400MB scan)
    build_adjacency_kernel<<<n_edges, 256, 0, stream>>>(H, edge_cnt, edge_nodes,
                                                        node_cnt, node_edges, n_nodes);
    // 3. all SIR steps in one persistent kernel with flag barriers
    sir_steps_kernel<<<COOP_BLOCKS, COOP_THREADS, 0, stream>>>(
        x, edge_cnt, edge_nodes, node_cnt, node_edges, beta, gamma,
        y, I, out, n_nodes, n_edges, steps, flags);
}